// Round 1
// baseline (3948.873 us; speedup 1.0000x reference)
//
#include <hip/hip_runtime.h>

#define NN 50000
#define NE 1600000
#define NFEAT 512
#define NHID 64
#define H1 8
#define NCLASS 16
#define ALPHA 0.2f
#define L1OUT 512   // H1*NHID

__device__ __forceinline__ float elu_f(float x) { return x > 0.0f ? x : expf(x) - 1.0f; }
__device__ __forceinline__ float edge_w(float logit) {
    // exp(-leaky_relu(logit, 0.2))
    return expf(-fmaxf(logit, ALPHA * logit));
}

// ---------------- GEMM1: h1[NN][512] = x[NN][512] @ W1[8][512][64] ----------------
// 64x64 output tile, BK=16, 256 threads, 4x4 per thread. blockIdx.y = head (64-col tile).
__global__ __launch_bounds__(256) void gemm1_k(const float* __restrict__ x,
                                               const float* __restrict__ W1,
                                               float* __restrict__ h1) {
    __shared__ float As[16][64];
    __shared__ float Bs[16][64];
    const int bm = blockIdx.x, bn = blockIdx.y;
    const int tid = threadIdx.x;
    const int tx = tid & 15, ty = tid >> 4;
    const int row0 = bm * 64;
    const int lm = tid >> 2;          // A: row within tile 0..63
    const int lk = (tid & 3) * 4;     // A: k offset 0,4,8,12
    const int bk = tid >> 4;          // B: k row 0..15
    const int bn4 = (tid & 15) * 4;   // B: col offset
    const float* Wbase = W1 + (size_t)bn * (512 * 64);
    float acc[4][4] = {};
    for (int k0 = 0; k0 < 512; k0 += 16) {
        int row = row0 + lm;
        float4 av = make_float4(0.f, 0.f, 0.f, 0.f);
        if (row < NN) av = *(const float4*)(x + (size_t)row * 512 + k0 + lk);
        As[lk + 0][lm] = av.x; As[lk + 1][lm] = av.y;
        As[lk + 2][lm] = av.z; As[lk + 3][lm] = av.w;
        float4 bv = *(const float4*)(Wbase + (size_t)(k0 + bk) * 64 + bn4);
        *(float4*)&Bs[bk][bn4] = bv;
        __syncthreads();
#pragma unroll
        for (int kk = 0; kk < 16; kk++) {
            float4 a = *(const float4*)&As[kk][ty * 4];
            float4 b = *(const float4*)&Bs[kk][tx * 4];
            float ar[4] = {a.x, a.y, a.z, a.w};
            float br[4] = {b.x, b.y, b.z, b.w};
#pragma unroll
            for (int i = 0; i < 4; i++)
#pragma unroll
                for (int j = 0; j < 4; j++) acc[i][j] += ar[i] * br[j];
        }
        __syncthreads();
    }
#pragma unroll
    for (int i = 0; i < 4; i++) {
        int row = row0 + ty * 4 + i;
        if (row < NN) {
            float4 o = make_float4(acc[i][0], acc[i][1], acc[i][2], acc[i][3]);
            *(float4*)(h1 + (size_t)row * 512 + bn * 64 + tx * 4) = o;
        }
    }
}

// ---------------- per-node per-head attention scores, layer 1 ----------------
// one wave per (node, head): s1s[h][n] = h1[n][h*64:] . a1[h][:64] ; s1d with a1[h][64:]
__global__ __launch_bounds__(256) void score1_k(const float* __restrict__ h1,
                                                const float* __restrict__ a1,
                                                float* __restrict__ s1s,
                                                float* __restrict__ s1d) {
    int gw = (blockIdx.x * 256 + threadIdx.x) >> 6;
    int lane = threadIdx.x & 63;
    if (gw >= NN * H1) return;
    int h = gw & 7, n = gw >> 3;
    float v = h1[(size_t)n * 512 + h * 64 + lane];
    float ss = v * a1[h * 128 + lane];
    float sd = v * a1[h * 128 + 64 + lane];
#pragma unroll
    for (int o = 32; o > 0; o >>= 1) {
        ss += __shfl_down(ss, o);
        sd += __shfl_down(sd, o);
    }
    if (lane == 0) { s1s[h * NN + n] = ss; s1d[h * NN + n] = sd; }
}

// ---------------- edge aggregation, layer 1 ----------------
// one wave per edge; lane covers 8 features (one per head row r)
__global__ __launch_bounds__(256) void edge1_k(const int* __restrict__ ei,
                                               const float* __restrict__ s1s,
                                               const float* __restrict__ s1d,
                                               const float* __restrict__ h1,
                                               float* __restrict__ agg1,
                                               float* __restrict__ rs1) {
    const int lane = threadIdx.x & 63;
    const int wid = (blockIdx.x * 256 + threadIdx.x) >> 6;
    const int nw = (gridDim.x * 256) >> 6;
    for (int e = wid; e < NE; e += nw) {
        const int src = ei[e], dst = ei[NE + e];
        const size_t sbase = (size_t)src * 512;
        const size_t dbase = (size_t)dst * 512;
        float w8 = 0.0f;
        if (lane < 8) {
            float logit = s1s[lane * NN + src] + s1d[lane * NN + dst];
            w8 = edge_w(logit);
            atomicAdd(&rs1[lane * NN + src], w8);
        }
#pragma unroll
        for (int r = 0; r < 8; r++) {
            int f = r * 64 + lane;
            float w = __shfl(w8, r);
            atomicAdd(&agg1[sbase + f], w * h1[dbase + f]);
        }
    }
}

// ---------------- finalize layer 1: h_cat = elu(agg1 / rowsum) in place ----------------
__global__ __launch_bounds__(256) void fin1_k(float4* __restrict__ agg1,
                                              const float* __restrict__ rs1) {
    size_t i4 = (size_t)blockIdx.x * 256 + threadIdx.x;
    if (i4 >= (size_t)NN * 128) return;
    int n = (int)(i4 >> 7);
    int rem = (int)(i4 & 127);
    int h = rem >> 4;
    float inv = 1.0f / rs1[h * NN + n];
    float4 v = agg1[i4];
    v.x = elu_f(v.x * inv);
    v.y = elu_f(v.y * inv);
    v.z = elu_f(v.z * inv);
    v.w = elu_f(v.w * inv);
    agg1[i4] = v;
}

// ---------------- GEMM2 + scores: h2[NN][16] = hcat @ W2[512][16]; s2s/s2d ----------------
// one wave per node: lane = chunk(4) x col(16); W2 staged in LDS.
__global__ __launch_bounds__(256) void gemm2_k(const float* __restrict__ hcat,
                                               const float* __restrict__ W2,
                                               const float* __restrict__ a2,
                                               float* __restrict__ h2,
                                               float* __restrict__ s2s,
                                               float* __restrict__ s2d) {
    __shared__ float Ws[512 * 16];
    for (int i = threadIdx.x; i < 512 * 16; i += 256) Ws[i] = W2[i];
    __syncthreads();
    const int wid = threadIdx.x >> 6;
    const int lane = threadIdx.x & 63;
    const int col = lane & 15;
    const int chunk = lane >> 4;
    for (int n = blockIdx.x * 4 + wid; n < NN; n += gridDim.x * 4) {
        const float* hr = hcat + (size_t)n * 512 + chunk * 128;
        float acc = 0.0f;
#pragma unroll 8
        for (int i = 0; i < 32; i++) {
            float4 v = *(const float4*)(hr + i * 4);
            int k = chunk * 128 + i * 4;
            acc += v.x * Ws[(k + 0) * 16 + col] + v.y * Ws[(k + 1) * 16 + col] +
                   v.z * Ws[(k + 2) * 16 + col] + v.w * Ws[(k + 3) * 16 + col];
        }
        acc += __shfl_down(acc, 32);
        acc += __shfl_down(acc, 16);
        if (lane < 16) {
            h2[(size_t)n * 16 + col] = acc;
            float ss = acc * a2[col];
            float sd = acc * a2[16 + col];
#pragma unroll
            for (int o = 8; o > 0; o >>= 1) {
                ss += __shfl_down(ss, o);
                sd += __shfl_down(sd, o);
            }
            if (lane == 0) { s2s[n] = ss; s2d[n] = sd; }
        }
    }
}

// ---------------- edge aggregation, layer 2 (16 feats/edge) ----------------
__global__ __launch_bounds__(256) void edge2_k(const int* __restrict__ ei,
                                               const float* __restrict__ s2s,
                                               const float* __restrict__ s2d,
                                               const float* __restrict__ h2,
                                               float* __restrict__ agg2,
                                               float* __restrict__ rs2) {
    const int t = threadIdx.x;
    const int le = t >> 4;
    const int f = t & 15;
    for (int e0 = blockIdx.x * 16; e0 < NE; e0 += gridDim.x * 16) {
        int e = e0 + le;
        if (e < NE) {
            int src = ei[e], dst = ei[NE + e];
            float w = edge_w(s2s[src] + s2d[dst]);
            atomicAdd(&agg2[(size_t)src * 16 + f], w * h2[(size_t)dst * 16 + f]);
            if (f == 0) atomicAdd(&rs2[src], w);
        }
    }
}

// ---------------- finalize: elu then log_softmax over 16 classes ----------------
__global__ __launch_bounds__(256) void fin2_k(const float* __restrict__ agg2,
                                              const float* __restrict__ rs2,
                                              float* __restrict__ out) {
    int n = blockIdx.x * 256 + threadIdx.x;
    if (n >= NN) return;
    float inv = 1.0f / rs2[n];
    float v[16];
    float m = -1e30f;
#pragma unroll
    for (int i = 0; i < 16; i++) {
        float t = elu_f(agg2[(size_t)n * 16 + i] * inv);
        v[i] = t;
        m = fmaxf(m, t);
    }
    float s = 0.0f;
#pragma unroll
    for (int i = 0; i < 16; i++) s += expf(v[i] - m);
    float ls = logf(s) + m;
#pragma unroll
    for (int i = 0; i < 16; i++) out[(size_t)n * 16 + i] = v[i] - ls;
}

extern "C" void kernel_launch(void* const* d_in, const int* in_sizes, int n_in,
                              void* d_out, int out_size, void* d_ws, size_t ws_size,
                              hipStream_t stream) {
    const float* x  = (const float*)d_in[0];
    const int*   ei = (const int*)d_in[1];
    const float* W1 = (const float*)d_in[2];
    const float* a1 = (const float*)d_in[3];
    const float* W2 = (const float*)d_in[4];
    const float* a2 = (const float*)d_in[5];
    float* out = (float*)d_out;

    float* ws = (float*)d_ws;
    float* h1   = ws;                         // 25,600,000
    float* agg1 = h1 + (size_t)NN * 512;      // 25,600,000
    float* s1s  = agg1 + (size_t)NN * 512;    // 400,000
    float* s1d  = s1s + (size_t)NN * H1;      // 400,000
    float* rs1  = s1d + (size_t)NN * H1;      // 400,000
    float* h2   = rs1 + (size_t)NN * H1;      // 800,000
    float* agg2 = h2 + (size_t)NN * 16;       // 800,000
    float* s2s  = agg2 + (size_t)NN * 16;     // 50,000
    float* s2d  = s2s + NN;                   // 50,000
    float* rs2  = s2d + NN;                   // 50,000

    // zero accumulators (ws is poisoned before every call)
    hipMemsetAsync(agg1, 0, (size_t)NN * 512 * 4, stream);
    hipMemsetAsync(rs1, 0, (size_t)NN * H1 * 4, stream);
    hipMemsetAsync(agg2, 0, (size_t)NN * 16 * 4, stream);
    hipMemsetAsync(rs2, 0, (size_t)NN * 4, stream);

    gemm1_k<<<dim3(782, 8), 256, 0, stream>>>(x, W1, h1);
    score1_k<<<(NN * H1 * 64) / 256, 256, 0, stream>>>(h1, a1, s1s, s1d);
    edge1_k<<<4096, 256, 0, stream>>>(ei, s1s, s1d, h1, agg1, rs1);
    fin1_k<<<25000, 256, 0, stream>>>((float4*)agg1, rs1);
    gemm2_k<<<2048, 256, 0, stream>>>(agg1, W2, a2, h2, s2s, s2d);
    edge2_k<<<8192, 256, 0, stream>>>(ei, s2s, s2d, h2, agg2, rs2);
    fin2_k<<<196, 256, 0, stream>>>(agg2, rs2, out);
}

// Round 2
// 1366.683 us; speedup vs baseline: 2.8894x; 2.8894x over previous
//
#include <hip/hip_runtime.h>

#define NN 50000
#define NE 1600000
#define NFEAT 512
#define NHID 64
#define H1 8
#define NCLASS 16
#define ALPHA 0.2f

__device__ __forceinline__ float elu_f(float x) { return x > 0.0f ? x : expf(x) - 1.0f; }
__device__ __forceinline__ float edge_w(float logit) {
    // exp(-leaky_relu(logit, 0.2))
    return expf(-fmaxf(logit, ALPHA * logit));
}

// ---------------- GEMM1: h1[NN][512] = x[NN][512] @ W1[8][512][64] ----------------
__global__ __launch_bounds__(256) void gemm1_k(const float* __restrict__ x,
                                               const float* __restrict__ W1,
                                               float* __restrict__ h1) {
    __shared__ float As[16][64];
    __shared__ float Bs[16][64];
    const int bm = blockIdx.x, bn = blockIdx.y;
    const int tid = threadIdx.x;
    const int tx = tid & 15, ty = tid >> 4;
    const int row0 = bm * 64;
    const int lm = tid >> 2;
    const int lk = (tid & 3) * 4;
    const int bk = tid >> 4;
    const int bn4 = (tid & 15) * 4;
    const float* Wbase = W1 + (size_t)bn * (512 * 64);
    float acc[4][4] = {};
    for (int k0 = 0; k0 < 512; k0 += 16) {
        int row = row0 + lm;
        float4 av = make_float4(0.f, 0.f, 0.f, 0.f);
        if (row < NN) av = *(const float4*)(x + (size_t)row * 512 + k0 + lk);
        As[lk + 0][lm] = av.x; As[lk + 1][lm] = av.y;
        As[lk + 2][lm] = av.z; As[lk + 3][lm] = av.w;
        float4 bv = *(const float4*)(Wbase + (size_t)(k0 + bk) * 64 + bn4);
        *(float4*)&Bs[bk][bn4] = bv;
        __syncthreads();
#pragma unroll
        for (int kk = 0; kk < 16; kk++) {
            float4 a = *(const float4*)&As[kk][ty * 4];
            float4 b = *(const float4*)&Bs[kk][tx * 4];
            float ar[4] = {a.x, a.y, a.z, a.w};
            float br[4] = {b.x, b.y, b.z, b.w};
#pragma unroll
            for (int i = 0; i < 4; i++)
#pragma unroll
                for (int j = 0; j < 4; j++) acc[i][j] += ar[i] * br[j];
        }
        __syncthreads();
    }
#pragma unroll
    for (int i = 0; i < 4; i++) {
        int row = row0 + ty * 4 + i;
        if (row < NN) {
            float4 o = make_float4(acc[i][0], acc[i][1], acc[i][2], acc[i][3]);
            *(float4*)(h1 + (size_t)row * 512 + bn * 64 + tx * 4) = o;
        }
    }
}

// ---------------- per-node per-head attention scores, layer 1 ----------------
__global__ __launch_bounds__(256) void score1_k(const float* __restrict__ h1,
                                                const float* __restrict__ a1,
                                                float* __restrict__ s1s,
                                                float* __restrict__ s1d) {
    int gw = (blockIdx.x * 256 + threadIdx.x) >> 6;
    int lane = threadIdx.x & 63;
    if (gw >= NN * H1) return;
    int h = gw & 7, n = gw >> 3;
    float v = h1[(size_t)n * 512 + h * 64 + lane];
    float ss = v * a1[h * 128 + lane];
    float sd = v * a1[h * 128 + 64 + lane];
#pragma unroll
    for (int o = 32; o > 0; o >>= 1) {
        ss += __shfl_down(ss, o);
        sd += __shfl_down(sd, o);
    }
    if (lane == 0) { s1s[h * NN + n] = ss; s1d[h * NN + n] = sd; }
}

// ---------------- CSR build: histogram, scan, scatter ----------------
__global__ __launch_bounds__(256) void deg_k(const int* __restrict__ ei, int* __restrict__ deg) {
    int e = blockIdx.x * 256 + threadIdx.x;
    if (e < NE) atomicAdd(&deg[ei[e]], 1);
}

__global__ __launch_bounds__(1024) void scan_k(const int* __restrict__ deg,
                                               int* __restrict__ rowptr) {
    __shared__ int wsum[16];
    __shared__ int carry_s;
    const int tid = threadIdx.x;
    const int lane = tid & 63;
    const int wv = tid >> 6;
    if (tid == 0) carry_s = 0;
    __syncthreads();
    for (int base = 0; base < NN; base += 1024) {
        int i = base + tid;
        int v = (i < NN) ? deg[i] : 0;
        int s = v;
#pragma unroll
        for (int o = 1; o < 64; o <<= 1) {
            int t = __shfl_up(s, o);
            if (lane >= o) s += t;
        }
        if (lane == 63) wsum[wv] = s;
        __syncthreads();
        if (tid < 16) {
            int t = wsum[tid];
#pragma unroll
            for (int o = 1; o < 16; o <<= 1) {
                int u = __shfl_up(t, o);
                if (lane >= o) t += u;
            }
            wsum[tid] = t;
        }
        __syncthreads();
        int excl = carry_s + (wv > 0 ? wsum[wv - 1] : 0) + (s - v);
        if (i < NN) rowptr[i] = excl;
        __syncthreads();
        if (tid == 1023) carry_s += wsum[15];
        __syncthreads();
    }
    if (tid == 0) rowptr[NN] = carry_s;
}

__global__ __launch_bounds__(256) void scatter_k(const int* __restrict__ ei,
                                                 const int* __restrict__ rowptr,
                                                 int* __restrict__ cursor,
                                                 int* __restrict__ csr_dst) {
    int e = blockIdx.x * 256 + threadIdx.x;
    if (e < NE) {
        int src = ei[e];
        int pos = rowptr[src] + atomicAdd(&cursor[src], 1);
        csr_dst[pos] = ei[NE + e];
    }
}

// ---------------- layer-1 aggregation via CSR: one wave per node ----------------
// acc in registers, fused elu(acc/rowsum) epilogue -> hcat. No atomics.
__global__ __launch_bounds__(256) void agg1_k(const int* __restrict__ rowptr,
                                              const int* __restrict__ csr_dst,
                                              const float* __restrict__ s1s,
                                              const float* __restrict__ s1d,
                                              const float* __restrict__ h1,
                                              float* __restrict__ hcat) {
    const int n = (blockIdx.x * 256 + threadIdx.x) >> 6;
    const int lane = threadIdx.x & 63;
    if (n >= NN) return;
    const int beg = rowptr[n], end = rowptr[n + 1];
    const float ssrc = (lane < 8) ? s1s[lane * NN + n] : 0.f;
    float acc[8] = {};
    float rsum = 0.f;
    int dst = (beg < end) ? csr_dst[beg] : 0;
    for (int e = beg; e < end; e++) {
        int dnext = (e + 1 < end) ? csr_dst[e + 1] : 0;   // prefetch
        float w8 = 0.f;
        if (lane < 8) {
            w8 = edge_w(ssrc + s1d[lane * NN + dst]);
            rsum += w8;
        }
        const float* hd = h1 + (size_t)dst * 512;
#pragma unroll
        for (int r = 0; r < 8; r++) {
            float wv = __shfl(w8, r);
            acc[r] += wv * hd[r * 64 + lane];
        }
        dst = dnext;
    }
#pragma unroll
    for (int r = 0; r < 8; r++) {
        float rs = __shfl(rsum, r);
        hcat[(size_t)n * 512 + r * 64 + lane] = elu_f(acc[r] / rs);
    }
}

// ---------------- GEMM2 + scores ----------------
__global__ __launch_bounds__(256) void gemm2_k(const float* __restrict__ hcat,
                                               const float* __restrict__ W2,
                                               const float* __restrict__ a2,
                                               float* __restrict__ h2,
                                               float* __restrict__ s2s,
                                               float* __restrict__ s2d) {
    __shared__ float Ws[512 * 16];
    for (int i = threadIdx.x; i < 512 * 16; i += 256) Ws[i] = W2[i];
    __syncthreads();
    const int wid = threadIdx.x >> 6;
    const int lane = threadIdx.x & 63;
    const int col = lane & 15;
    const int chunk = lane >> 4;
    for (int n = blockIdx.x * 4 + wid; n < NN; n += gridDim.x * 4) {
        const float* hr = hcat + (size_t)n * 512 + chunk * 128;
        float acc = 0.0f;
#pragma unroll 8
        for (int i = 0; i < 32; i++) {
            float4 v = *(const float4*)(hr + i * 4);
            int k = chunk * 128 + i * 4;
            acc += v.x * Ws[(k + 0) * 16 + col] + v.y * Ws[(k + 1) * 16 + col] +
                   v.z * Ws[(k + 2) * 16 + col] + v.w * Ws[(k + 3) * 16 + col];
        }
        acc += __shfl_down(acc, 32);
        acc += __shfl_down(acc, 16);
        if (lane < 16) {
            h2[(size_t)n * 16 + col] = acc;
            float ss = acc * a2[col];
            float sd = acc * a2[16 + col];
#pragma unroll
            for (int o = 8; o > 0; o >>= 1) {
                ss += __shfl_down(ss, o);
                sd += __shfl_down(sd, o);
            }
            if (lane == 0) { s2s[n] = ss; s2d[n] = sd; }
        }
    }
}

// ---------------- layer-2 aggregation via CSR + fused log_softmax ----------------
// one wave per node; 4 edges in flight (16 lanes each). No atomics.
__global__ __launch_bounds__(256) void agg2_k(const int* __restrict__ rowptr,
                                              const int* __restrict__ csr_dst,
                                              const float* __restrict__ s2s,
                                              const float* __restrict__ s2d,
                                              const float* __restrict__ h2,
                                              float* __restrict__ out) {
    const int n = (blockIdx.x * 256 + threadIdx.x) >> 6;
    const int lane = threadIdx.x & 63;
    if (n >= NN) return;
    const int beg = rowptr[n], end = rowptr[n + 1];
    const float sn = s2s[n];
    const int sub = lane >> 4, f = lane & 15;
    float acc = 0.f, rsum = 0.f;
    for (int e = beg + sub; e < end; e += 4) {
        int dst = csr_dst[e];
        float wv = edge_w(sn + s2d[dst]);
        acc += wv * h2[(size_t)dst * 16 + f];
        rsum += wv;
    }
    acc += __shfl_down(acc, 32);
    acc += __shfl_down(acc, 16);
    rsum += __shfl_down(rsum, 32);
    rsum += __shfl_down(rsum, 16);
    if (lane < 16) {
        float v = elu_f(acc / rsum);
        float m = v;
#pragma unroll
        for (int o = 8; o > 0; o >>= 1) m = fmaxf(m, __shfl_xor(m, o));
        float ex = expf(v - m), s = ex;
#pragma unroll
        for (int o = 8; o > 0; o >>= 1) s += __shfl_xor(s, o);
        out[(size_t)n * 16 + f] = v - (logf(s) + m);
    }
}

extern "C" void kernel_launch(void* const* d_in, const int* in_sizes, int n_in,
                              void* d_out, int out_size, void* d_ws, size_t ws_size,
                              hipStream_t stream) {
    const float* x  = (const float*)d_in[0];
    const int*   ei = (const int*)d_in[1];
    const float* W1 = (const float*)d_in[2];
    const float* a1 = (const float*)d_in[3];
    const float* W2 = (const float*)d_in[4];
    const float* a2 = (const float*)d_in[5];
    float* out = (float*)d_out;

    float* ws = (float*)d_ws;
    float* h1   = ws;                                  // 25.6M floats (dead after agg1_k)
    float* hcat = h1 + (size_t)NN * 512;               // 25.6M floats
    float* s1s  = hcat + (size_t)NN * 512;             // 0.4M
    float* s1d  = s1s + (size_t)NN * H1;               // 0.4M
    int*   deg    = (int*)(s1d + (size_t)NN * H1);     // 50000
    int*   cursor = deg + NN;                          // 50000
    int*   rowptr = cursor + NN;                       // 50001
    int*   csr_dst = rowptr + NN + 1;                  // 1.6M
    // layer-2 node data aliases h1 (h1 dead once agg1_k completes)
    float* h2  = h1;                                   // 0.8M
    float* s2s = h1 + (size_t)NN * 16;                 // 50000
    float* s2d = s2s + NN;                             // 50000

    hipMemsetAsync(deg, 0, 2 * NN * sizeof(int), stream);  // deg + cursor

    gemm1_k<<<dim3(782, 8), 256, 0, stream>>>(x, W1, h1);
    score1_k<<<(NN * H1 * 64) / 256, 256, 0, stream>>>(h1, a1, s1s, s1d);
    deg_k<<<(NE + 255) / 256, 256, 0, stream>>>(ei, deg);
    scan_k<<<1, 1024, 0, stream>>>(deg, rowptr);
    scatter_k<<<(NE + 255) / 256, 256, 0, stream>>>(ei, rowptr, cursor, csr_dst);
    agg1_k<<<(NN + 3) / 4, 256, 0, stream>>>(rowptr, csr_dst, s1s, s1d, h1, hcat);
    gemm2_k<<<2048, 256, 0, stream>>>(hcat, W2, a2, h2, s2s, s2d);
    agg2_k<<<(NN + 3) / 4, 256, 0, stream>>>(rowptr, csr_dst, s2s, s2d, h2, out);
}

// Round 3
// 843.370 us; speedup vs baseline: 4.6823x; 1.6205x over previous
//
#include <hip/hip_runtime.h>

#define NN 50000
#define NE 1600000
#define NFEAT 512
#define NHID 64
#define H1 8
#define NCLASS 16
#define ALPHA 0.2f

typedef __attribute__((ext_vector_type(8))) short short8;
typedef __attribute__((ext_vector_type(4))) float floatx4;

__device__ __forceinline__ float elu_f(float x) { return x > 0.0f ? x : expf(x) - 1.0f; }
__device__ __forceinline__ float edge_w(float logit) {
    return expf(-fmaxf(logit, ALPHA * logit));   // exp(-leaky_relu)
}
__device__ __forceinline__ ushort f2bf(float f) {
    uint u = __float_as_uint(f);
    return (ushort)((u + 0x7FFFu + ((u >> 16) & 1)) >> 16);   // RNE
}
__device__ __forceinline__ uint packbf2(float lo, float hi) {
    return (uint)f2bf(lo) | ((uint)f2bf(hi) << 16);
}
__device__ __forceinline__ float bflo(uint v) { return __uint_as_float(v << 16); }
__device__ __forceinline__ float bfhi(uint v) { return __uint_as_float(v & 0xFFFF0000u); }

// ---------------- cast x -> bf16 ----------------
__global__ __launch_bounds__(256) void cast_x(const float4* __restrict__ x,
                                              uint4* __restrict__ xb) {
    size_t i = (size_t)blockIdx.x * 256 + threadIdx.x;
    if (i >= (size_t)NN * 512 / 8) return;
    float4 a = x[2 * i], b = x[2 * i + 1];
    uint4 o;
    o.x = packbf2(a.x, a.y);
    o.y = packbf2(a.z, a.w);
    o.z = packbf2(b.x, b.y);
    o.w = packbf2(b.z, b.w);
    xb[i] = o;
}

// ---------------- pack W1[8][512][64] -> Wt[c][k] bf16 (c = head*64+hid) ----------------
__global__ __launch_bounds__(256) void pack_w(const float* __restrict__ W1,
                                              ushort* __restrict__ Wt) {
    int i = blockIdx.x * 256 + threadIdx.x;
    if (i >= 512 * 512) return;
    int c = i >> 9, k = i & 511;
    int head = c >> 6, hid = c & 63;
    Wt[i] = f2bf(W1[(head * 512 + k) * 64 + hid]);
}

// ---------------- GEMM1 (bf16 MFMA) + fused attention scores ----------------
// grid (782, 8): 64 rows x 64 cols (one head) per block; 4 waves, each 16 rows.
__global__ __launch_bounds__(256) void gemm1_k(const ushort* __restrict__ xb,
                                               const ushort* __restrict__ Wt,
                                               const float* __restrict__ a1,
                                               ushort* __restrict__ h1b,
                                               float* __restrict__ s1s,
                                               float* __restrict__ s1d) {
    __shared__ ushort As[64 * 32];   // [m][k]
    __shared__ ushort Bs[64 * 32];   // [n][k]
    const int tid = threadIdx.x;
    const int wv = tid >> 6, lane = tid & 63;
    const int quad = lane >> 4, l16 = lane & 15;
    const int row0 = blockIdx.x * 64;
    const int head = blockIdx.y;
    const int sm = tid >> 2, sk = (tid & 3) * 8;   // staging: thread -> 8 ushorts
    floatx4 acc[4];
#pragma unroll
    for (int ct = 0; ct < 4; ct++) acc[ct] = (floatx4){0.f, 0.f, 0.f, 0.f};

    for (int k0 = 0; k0 < 512; k0 += 32) {
        int arow = row0 + sm;
        uint4 av = make_uint4(0u, 0u, 0u, 0u);
        if (arow < NN) av = *(const uint4*)(xb + (size_t)arow * 512 + k0 + sk);
        *(uint4*)(As + sm * 32 + sk) = av;
        uint4 bv = *(const uint4*)(Wt + (size_t)(head * 64 + sm) * 512 + k0 + sk);
        *(uint4*)(Bs + sm * 32 + sk) = bv;
        __syncthreads();
        short8 afrag = *(const short8*)(As + (wv * 16 + l16) * 32 + quad * 8);
#pragma unroll
        for (int ct = 0; ct < 4; ct++) {
            short8 bfrag = *(const short8*)(Bs + (ct * 16 + l16) * 32 + quad * 8);
            acc[ct] = __builtin_amdgcn_mfma_f32_16x16x32_bf16(afrag, bfrag, acc[ct], 0, 0, 0);
        }
        __syncthreads();
    }

    // epilogue: store bf16 h1, fused s_src/s_dst scores
    const int rbase = row0 + wv * 16 + quad * 4;
    float ssr[4] = {0.f, 0.f, 0.f, 0.f};
    float sdr[4] = {0.f, 0.f, 0.f, 0.f};
#pragma unroll
    for (int ct = 0; ct < 4; ct++) {
        int col = ct * 16 + l16;
        float as_ = a1[head * 128 + col];
        float ad_ = a1[head * 128 + 64 + col];
#pragma unroll
        for (int r = 0; r < 4; r++) {
            float v = acc[ct][r];
            ssr[r] += v * as_;
            sdr[r] += v * ad_;
            int row = rbase + r;
            if (row < NN) h1b[(size_t)row * 512 + head * 64 + col] = f2bf(v);
        }
    }
#pragma unroll
    for (int r = 0; r < 4; r++) {
#pragma unroll
        for (int o = 1; o < 16; o <<= 1) {
            ssr[r] += __shfl_xor(ssr[r], o);
            sdr[r] += __shfl_xor(sdr[r], o);
        }
        int row = rbase + r;
        if (l16 == 0 && row < NN) {
            s1s[head * NN + row] = ssr[r];
            s1d[head * NN + row] = sdr[r];
        }
    }
}

// ---------------- CSR build ----------------
__global__ __launch_bounds__(256) void deg_k(const int* __restrict__ ei, int* __restrict__ deg) {
    int e = blockIdx.x * 256 + threadIdx.x;
    if (e < NE) atomicAdd(&deg[ei[e]], 1);
}

__global__ __launch_bounds__(1024) void scan_k(const int* __restrict__ deg,
                                               int* __restrict__ rowptr) {
    __shared__ int wsum[16];
    __shared__ int carry_s;
    const int tid = threadIdx.x;
    const int lane = tid & 63;
    const int wv = tid >> 6;
    if (tid == 0) carry_s = 0;
    __syncthreads();
    for (int base = 0; base < NN; base += 1024) {
        int i = base + tid;
        int v = (i < NN) ? deg[i] : 0;
        int s = v;
#pragma unroll
        for (int o = 1; o < 64; o <<= 1) {
            int t = __shfl_up(s, o);
            if (lane >= o) s += t;
        }
        if (lane == 63) wsum[wv] = s;
        __syncthreads();
        if (tid < 16) {
            int t = wsum[tid];
#pragma unroll
            for (int o = 1; o < 16; o <<= 1) {
                int u = __shfl_up(t, o);
                if (lane >= o) t += u;
            }
            wsum[tid] = t;
        }
        __syncthreads();
        int excl = carry_s + (wv > 0 ? wsum[wv - 1] : 0) + (s - v);
        if (i < NN) rowptr[i] = excl;
        __syncthreads();
        if (tid == 1023) carry_s += wsum[15];
        __syncthreads();
    }
    if (tid == 0) rowptr[NN] = carry_s;
}

__global__ __launch_bounds__(256) void scatter_k(const int* __restrict__ ei,
                                                 const int* __restrict__ rowptr,
                                                 int* __restrict__ cursor,
                                                 int* __restrict__ csr_dst) {
    int e = blockIdx.x * 256 + threadIdx.x;
    if (e < NE) {
        int src = ei[e];
        int pos = rowptr[src] + atomicAdd(&cursor[src], 1);
        csr_dst[pos] = ei[NE + e];
    }
}

// ---------------- layer-1 aggregation: one wave per node, bf16 gather ----------------
__global__ __launch_bounds__(256) void agg1_k(const int* __restrict__ rowptr,
                                              const int* __restrict__ csr_dst,
                                              const float* __restrict__ s1s,
                                              const float* __restrict__ s1d,
                                              const uint* __restrict__ h1b2,
                                              uint* __restrict__ hcat2) {
    const int n = (blockIdx.x * 256 + threadIdx.x) >> 6;
    const int lane = threadIdx.x & 63;
    if (n >= NN) return;
    const int beg = rowptr[n], end = rowptr[n + 1];
    const float ssrc = (lane < 8) ? s1s[lane * NN + n] : 0.f;
    const int hsel = lane >> 5;   // head = r2*2 + hsel for this lane's features
    float2 acc[4] = {};
    float rsum = 0.f;
    for (int e = beg; e < end; e++) {
        int dst = csr_dst[e];
        float w8 = 0.f;
        if (lane < 8) {
            w8 = edge_w(ssrc + s1d[lane * NN + dst]);
            rsum += w8;
        }
        const uint* hd = h1b2 + (size_t)dst * 256;
#pragma unroll
        for (int r2 = 0; r2 < 4; r2++) {
            uint v = hd[r2 * 64 + lane];
            float w = __shfl(w8, r2 * 2 + hsel);
            acc[r2].x += w * bflo(v);
            acc[r2].y += w * bfhi(v);
        }
    }
#pragma unroll
    for (int r2 = 0; r2 < 4; r2++) {
        float rs = __shfl(rsum, r2 * 2 + hsel);
        float inv = 1.0f / rs;
        hcat2[(size_t)n * 256 + r2 * 64 + lane] =
            packbf2(elu_f(acc[r2].x * inv), elu_f(acc[r2].y * inv));
    }
}

// ---------------- GEMM2 (bf16 in) + scores ----------------
__global__ __launch_bounds__(256) void gemm2_k(const uint* __restrict__ hcat2,
                                               const float* __restrict__ W2,
                                               const float* __restrict__ a2,
                                               float* __restrict__ h2,
                                               float* __restrict__ s2s,
                                               float* __restrict__ s2d) {
    __shared__ float Ws[512 * 16];
    for (int i = threadIdx.x; i < 512 * 16; i += 256) Ws[i] = W2[i];
    __syncthreads();
    const int wid = threadIdx.x >> 6;
    const int lane = threadIdx.x & 63;
    const int col = lane & 15;
    const int chunk = lane >> 4;
    for (int n = blockIdx.x * 4 + wid; n < NN; n += gridDim.x * 4) {
        const uint* hr = hcat2 + (size_t)n * 256 + chunk * 64;
        float acc = 0.0f;
#pragma unroll 4
        for (int i = 0; i < 16; i++) {
            uint4 v = *(const uint4*)(hr + i * 4);
            int k = chunk * 128 + i * 8;
            acc += bflo(v.x) * Ws[(k + 0) * 16 + col] + bfhi(v.x) * Ws[(k + 1) * 16 + col] +
                   bflo(v.y) * Ws[(k + 2) * 16 + col] + bfhi(v.y) * Ws[(k + 3) * 16 + col] +
                   bflo(v.z) * Ws[(k + 4) * 16 + col] + bfhi(v.z) * Ws[(k + 5) * 16 + col] +
                   bflo(v.w) * Ws[(k + 6) * 16 + col] + bfhi(v.w) * Ws[(k + 7) * 16 + col];
        }
        acc += __shfl_down(acc, 32);
        acc += __shfl_down(acc, 16);
        if (lane < 16) {
            h2[(size_t)n * 16 + col] = acc;
            float ss = acc * a2[col];
            float sd = acc * a2[16 + col];
#pragma unroll
            for (int o = 8; o > 0; o >>= 1) {
                ss += __shfl_down(ss, o);
                sd += __shfl_down(sd, o);
            }
            if (lane == 0) { s2s[n] = ss; s2d[n] = sd; }
        }
    }
}

// ---------------- layer-2 aggregation + fused log_softmax ----------------
__global__ __launch_bounds__(256) void agg2_k(const int* __restrict__ rowptr,
                                              const int* __restrict__ csr_dst,
                                              const float* __restrict__ s2s,
                                              const float* __restrict__ s2d,
                                              const float* __restrict__ h2,
                                              float* __restrict__ out) {
    const int n = (blockIdx.x * 256 + threadIdx.x) >> 6;
    const int lane = threadIdx.x & 63;
    if (n >= NN) return;
    const int beg = rowptr[n], end = rowptr[n + 1];
    const float sn = s2s[n];
    const int sub = lane >> 4, f = lane & 15;
    float acc = 0.f, rsum = 0.f;
    for (int e = beg + sub; e < end; e += 4) {
        int dst = csr_dst[e];
        float wv = edge_w(sn + s2d[dst]);
        acc += wv * h2[(size_t)dst * 16 + f];
        rsum += wv;
    }
    acc += __shfl_down(acc, 32);
    acc += __shfl_down(acc, 16);
    rsum += __shfl_down(rsum, 32);
    rsum += __shfl_down(rsum, 16);
    if (lane < 16) {
        float v = elu_f(acc / rsum);
        float m = v;
#pragma unroll
        for (int o = 8; o > 0; o >>= 1) m = fmaxf(m, __shfl_xor(m, o));
        float ex = expf(v - m), s = ex;
#pragma unroll
        for (int o = 8; o > 0; o >>= 1) s += __shfl_xor(s, o);
        out[(size_t)n * 16 + f] = v - (logf(s) + m);
    }
}

extern "C" void kernel_launch(void* const* d_in, const int* in_sizes, int n_in,
                              void* d_out, int out_size, void* d_ws, size_t ws_size,
                              hipStream_t stream) {
    const float* x  = (const float*)d_in[0];
    const int*   ei = (const int*)d_in[1];
    const float* W1 = (const float*)d_in[2];
    const float* a1 = (const float*)d_in[3];
    const float* W2 = (const float*)d_in[4];
    const float* a2 = (const float*)d_in[5];
    float* out = (float*)d_out;

    ushort* xb    = (ushort*)d_ws;                 // 25.6M ushort
    ushort* h1b   = xb + (size_t)NN * 512;         // 25.6M
    ushort* hcatb = h1b + (size_t)NN * 512;        // 25.6M
    ushort* Wt    = hcatb + (size_t)NN * 512;      // 262144
    float* s1s    = (float*)(Wt + 512 * 512);      // 400K floats
    float* s1d    = s1s + (size_t)NN * H1;         // 400K
    int* deg      = (int*)(s1d + (size_t)NN * H1); // 50000
    int* cursor   = deg + NN;                      // 50000
    int* rowptr   = cursor + NN;                   // 50001
    int* csr_dst  = rowptr + NN + 1;               // 1.6M
    float* h2     = (float*)(csr_dst + NE);        // 800K
    float* s2s    = h2 + (size_t)NN * 16;          // 50000
    float* s2d    = s2s + NN;                      // 50000

    hipMemsetAsync(deg, 0, 2 * NN * sizeof(int), stream);  // deg + cursor

    cast_x<<<12500, 256, 0, stream>>>((const float4*)x, (uint4*)xb);
    pack_w<<<1024, 256, 0, stream>>>(W1, Wt);
    deg_k<<<(NE + 255) / 256, 256, 0, stream>>>(ei, deg);
    scan_k<<<1, 1024, 0, stream>>>(deg, rowptr);
    scatter_k<<<(NE + 255) / 256, 256, 0, stream>>>(ei, rowptr, cursor, csr_dst);
    gemm1_k<<<dim3(782, 8), 256, 0, stream>>>(xb, Wt, a1, h1b, s1s, s1d);
    agg1_k<<<(NN + 3) / 4, 256, 0, stream>>>(rowptr, csr_dst, s1s, s1d,
                                             (const uint*)h1b, (uint*)hcatb);
    gemm2_k<<<2048, 256, 0, stream>>>((const uint*)hcatb, W2, a2, h2, s2s, s2d);
    agg2_k<<<(NN + 3) / 4, 256, 0, stream>>>(rowptr, csr_dst, s2s, s2d, h2, out);
}

// Round 4
// 774.252 us; speedup vs baseline: 5.1002x; 1.0893x over previous
//
#include <hip/hip_runtime.h>

#define NN 50000
#define NE 1600000
#define NFEAT 512
#define NHID 64
#define H1 8
#define NCLASS 16
#define ALPHA 0.2f

typedef __attribute__((ext_vector_type(8))) short short8;
typedef __attribute__((ext_vector_type(4))) float floatx4;

__device__ __forceinline__ float elu_f(float x) { return x > 0.0f ? x : expf(x) - 1.0f; }
__device__ __forceinline__ float edge_w(float logit) {
    return expf(-fmaxf(logit, ALPHA * logit));   // exp(-leaky_relu)
}
__device__ __forceinline__ ushort f2bf(float f) {
    uint u = __float_as_uint(f);
    return (ushort)((u + 0x7FFFu + ((u >> 16) & 1)) >> 16);   // RNE
}
__device__ __forceinline__ uint packbf2(float lo, float hi) {
    return (uint)f2bf(lo) | ((uint)f2bf(hi) << 16);
}
__device__ __forceinline__ float bflo(uint v) { return __uint_as_float(v << 16); }
__device__ __forceinline__ float bfhi(uint v) { return __uint_as_float(v & 0xFFFF0000u); }

// ---------------- cast x -> bf16 ----------------
__global__ __launch_bounds__(256) void cast_x(const float4* __restrict__ x,
                                              uint4* __restrict__ xb) {
    size_t i = (size_t)blockIdx.x * 256 + threadIdx.x;
    if (i >= (size_t)NN * 512 / 8) return;
    float4 a = x[2 * i], b = x[2 * i + 1];
    uint4 o;
    o.x = packbf2(a.x, a.y);
    o.y = packbf2(a.z, a.w);
    o.z = packbf2(b.x, b.y);
    o.w = packbf2(b.z, b.w);
    xb[i] = o;
}

// ---------------- pack W1[8][512][64] -> Wt[c][k] bf16 (c = head*64+hid) ----------------
__global__ __launch_bounds__(256) void pack_w(const float* __restrict__ W1,
                                              ushort* __restrict__ Wt) {
    int i = blockIdx.x * 256 + threadIdx.x;
    if (i >= 512 * 512) return;
    int c = i >> 9, k = i & 511;
    int head = c >> 6, hid = c & 63;
    Wt[i] = f2bf(W1[(head * 512 + k) * 64 + hid]);
}

// ---------------- GEMM1 (bf16 MFMA) 128x128 tile (2 heads) + fused scores ----------------
// grid (4, 391): blockIdx.x = col-block (fast dim -> same-row blocks adjacent for L2 A reuse)
__global__ __launch_bounds__(256) void gemm1_k(const ushort* __restrict__ xb,
                                               const ushort* __restrict__ Wt,
                                               const float* __restrict__ a1,
                                               ushort* __restrict__ h1b,
                                               float* __restrict__ s1s,
                                               float* __restrict__ s1d) {
    __shared__ ushort As[128 * 32];   // [m][k]
    __shared__ ushort Bs[128 * 32];   // [c][k]
    const int tid = threadIdx.x;
    const int wv = tid >> 6, lane = tid & 63;
    const int quad = lane >> 4, l16 = lane & 15;
    const int row0 = blockIdx.y * 128;
    const int col0 = blockIdx.x * 128;
    const int sm = tid >> 2, sk = (tid & 3) * 8;   // staging: 8 ushorts/thread/pass
    floatx4 acc[2][8];
#pragma unroll
    for (int rt = 0; rt < 2; rt++)
#pragma unroll
        for (int ct = 0; ct < 8; ct++) acc[rt][ct] = (floatx4){0.f, 0.f, 0.f, 0.f};

    for (int k0 = 0; k0 < 512; k0 += 32) {
#pragma unroll
        for (int p = 0; p < 2; p++) {
            int r = row0 + sm + p * 64;
            uint4 av = make_uint4(0u, 0u, 0u, 0u);
            if (r < NN) av = *(const uint4*)(xb + (size_t)r * 512 + k0 + sk);
            *(uint4*)(As + (sm + p * 64) * 32 + sk) = av;
            int c = col0 + sm + p * 64;
            uint4 bv = *(const uint4*)(Wt + (size_t)c * 512 + k0 + sk);
            *(uint4*)(Bs + (sm + p * 64) * 32 + sk) = bv;
        }
        __syncthreads();
        short8 a0 = *(const short8*)(As + (wv * 32 + l16) * 32 + quad * 8);
        short8 a1f = *(const short8*)(As + (wv * 32 + 16 + l16) * 32 + quad * 8);
#pragma unroll
        for (int ct = 0; ct < 8; ct++) {
            short8 bf = *(const short8*)(Bs + (ct * 16 + l16) * 32 + quad * 8);
            acc[0][ct] = __builtin_amdgcn_mfma_f32_16x16x32_bf16(a0, bf, acc[0][ct], 0, 0, 0);
            acc[1][ct] = __builtin_amdgcn_mfma_f32_16x16x32_bf16(a1f, bf, acc[1][ct], 0, 0, 0);
        }
        __syncthreads();
    }

    // epilogue: bf16 h1 stores + per-head fused scores
#pragma unroll
    for (int rt = 0; rt < 2; rt++) {
        const int rbase = row0 + wv * 32 + rt * 16 + quad * 4;
        float ss[2][4] = {}, sd[2][4] = {};
#pragma unroll
        for (int ct = 0; ct < 8; ct++) {
            int colg = col0 + ct * 16 + l16;
            int head = colg >> 6;
            int hh = ct >> 2;
            float avs = a1[head * 128 + (colg & 63)];
            float avd = a1[head * 128 + 64 + (colg & 63)];
#pragma unroll
            for (int r = 0; r < 4; r++) {
                float v = acc[rt][ct][r];
                ss[hh][r] += v * avs;
                sd[hh][r] += v * avd;
                int row = rbase + r;
                if (row < NN) h1b[(size_t)row * 512 + colg] = f2bf(v);
            }
        }
#pragma unroll
        for (int hh = 0; hh < 2; hh++)
#pragma unroll
            for (int r = 0; r < 4; r++) {
                float a_ = ss[hh][r], b_ = sd[hh][r];
#pragma unroll
                for (int o = 1; o < 16; o <<= 1) {
                    a_ += __shfl_xor(a_, o);
                    b_ += __shfl_xor(b_, o);
                }
                int row = rbase + r;
                if (l16 == 0 && row < NN) {
                    int head = (col0 >> 6) + hh;
                    s1s[head * NN + row] = a_;
                    s1d[head * NN + row] = b_;
                }
            }
    }
}

// ---------------- CSR build ----------------
__global__ __launch_bounds__(256) void deg_k(const int* __restrict__ ei, int* __restrict__ deg) {
    int e = blockIdx.x * 256 + threadIdx.x;
    if (e < NE) atomicAdd(&deg[ei[e]], 1);
}

__global__ __launch_bounds__(1024) void scan_k(const int* __restrict__ deg,
                                               int* __restrict__ rowptr) {
    __shared__ int wsum[16];
    __shared__ int carry_s;
    const int tid = threadIdx.x;
    const int lane = tid & 63;
    const int wv = tid >> 6;
    if (tid == 0) carry_s = 0;
    __syncthreads();
    for (int base = 0; base < NN; base += 1024) {
        int i = base + tid;
        int v = (i < NN) ? deg[i] : 0;
        int s = v;
#pragma unroll
        for (int o = 1; o < 64; o <<= 1) {
            int t = __shfl_up(s, o);
            if (lane >= o) s += t;
        }
        if (lane == 63) wsum[wv] = s;
        __syncthreads();
        if (tid < 16) {
            int t = wsum[tid];
#pragma unroll
            for (int o = 1; o < 16; o <<= 1) {
                int u = __shfl_up(t, o);
                if (lane >= o) t += u;
            }
            wsum[tid] = t;
        }
        __syncthreads();
        int excl = carry_s + (wv > 0 ? wsum[wv - 1] : 0) + (s - v);
        if (i < NN) rowptr[i] = excl;
        __syncthreads();
        if (tid == 1023) carry_s += wsum[15];
        __syncthreads();
    }
    if (tid == 0) rowptr[NN] = carry_s;
}

__global__ __launch_bounds__(256) void scatter_k(const int* __restrict__ ei,
                                                 const int* __restrict__ rowptr,
                                                 int* __restrict__ cursor,
                                                 int* __restrict__ csr_dst) {
    int e = blockIdx.x * 256 + threadIdx.x;
    if (e < NE) {
        int src = ei[e];
        int pos = rowptr[src] + atomicAdd(&cursor[src], 1);
        csr_dst[pos] = ei[NE + e];
    }
}

// ---------------- layer-1 aggregation: one wave per node ----------------
// lane l covers uint4 [4l..4l+3] of the dst row => single head (l>>3), one dwordx4/edge.
// Row dsts bitonic-sorted in-wave so all waves sweep dst space in lockstep (L2 locality).
__global__ __launch_bounds__(256) void agg1_k(const int* __restrict__ rowptr,
                                              const int* __restrict__ csr_dst,
                                              const float* __restrict__ s1s,
                                              const float* __restrict__ s1d,
                                              const uint4* __restrict__ hb,
                                              uint4* __restrict__ hcat4) {
    const int n = (blockIdx.x * 256 + threadIdx.x) >> 6;
    const int lane = threadIdx.x & 63;
    if (n >= NN) return;
    const int beg = rowptr[n], end = rowptr[n + 1];
    const int deg = end - beg;
    const float ssrc = (lane < 8) ? s1s[lane * NN + n] : 0.f;
    const int myhead = lane >> 3;
    float2 acc[4] = {};
    float rsum = 0.f;

    if (deg <= 64) {
        int d = (lane < deg) ? csr_dst[beg + lane] : 0x7fffffff;
#pragma unroll
        for (int k = 2; k <= 64; k <<= 1)
            for (int j = k >> 1; j > 0; j >>= 1) {
                int o = __shfl_xor(d, j);
                bool up = (lane & k) == 0;
                bool lower = (lane & j) == 0;
                d = (up == lower) ? min(d, o) : max(d, o);
            }
        int k = 0;
        for (; k + 1 < deg; k += 2) {
            int d0 = __shfl(d, k), d1 = __shfl(d, k + 1);
            float w0 = 0.f, w1 = 0.f;
            if (lane < 8) {
                w0 = edge_w(ssrc + s1d[lane * NN + d0]);
                w1 = edge_w(ssrc + s1d[lane * NN + d1]);
                rsum += w0 + w1;
            }
            uint4 v0 = hb[(size_t)d0 * 64 + lane];
            uint4 v1 = hb[(size_t)d1 * 64 + lane];
            float wa = __shfl(w0, myhead);
            float wb = __shfl(w1, myhead);
            acc[0].x += wa * bflo(v0.x); acc[0].y += wa * bfhi(v0.x);
            acc[1].x += wa * bflo(v0.y); acc[1].y += wa * bfhi(v0.y);
            acc[2].x += wa * bflo(v0.z); acc[2].y += wa * bfhi(v0.z);
            acc[3].x += wa * bflo(v0.w); acc[3].y += wa * bfhi(v0.w);
            acc[0].x += wb * bflo(v1.x); acc[0].y += wb * bfhi(v1.x);
            acc[1].x += wb * bflo(v1.y); acc[1].y += wb * bfhi(v1.y);
            acc[2].x += wb * bflo(v1.z); acc[2].y += wb * bfhi(v1.z);
            acc[3].x += wb * bflo(v1.w); acc[3].y += wb * bfhi(v1.w);
        }
        if (k < deg) {
            int d0 = __shfl(d, k);
            float w0 = 0.f;
            if (lane < 8) {
                w0 = edge_w(ssrc + s1d[lane * NN + d0]);
                rsum += w0;
            }
            uint4 v0 = hb[(size_t)d0 * 64 + lane];
            float wa = __shfl(w0, myhead);
            acc[0].x += wa * bflo(v0.x); acc[0].y += wa * bfhi(v0.x);
            acc[1].x += wa * bflo(v0.y); acc[1].y += wa * bfhi(v0.y);
            acc[2].x += wa * bflo(v0.z); acc[2].y += wa * bfhi(v0.z);
            acc[3].x += wa * bflo(v0.w); acc[3].y += wa * bfhi(v0.w);
        }
    } else {
        int k = 0;
        for (; k + 1 < deg; k += 2) {
            int d0 = csr_dst[beg + k], d1 = csr_dst[beg + k + 1];
            float w0 = 0.f, w1 = 0.f;
            if (lane < 8) {
                w0 = edge_w(ssrc + s1d[lane * NN + d0]);
                w1 = edge_w(ssrc + s1d[lane * NN + d1]);
                rsum += w0 + w1;
            }
            uint4 v0 = hb[(size_t)d0 * 64 + lane];
            uint4 v1 = hb[(size_t)d1 * 64 + lane];
            float wa = __shfl(w0, myhead);
            float wb = __shfl(w1, myhead);
            acc[0].x += wa * bflo(v0.x); acc[0].y += wa * bfhi(v0.x);
            acc[1].x += wa * bflo(v0.y); acc[1].y += wa * bfhi(v0.y);
            acc[2].x += wa * bflo(v0.z); acc[2].y += wa * bfhi(v0.z);
            acc[3].x += wa * bflo(v0.w); acc[3].y += wa * bfhi(v0.w);
            acc[0].x += wb * bflo(v1.x); acc[0].y += wb * bfhi(v1.x);
            acc[1].x += wb * bflo(v1.y); acc[1].y += wb * bfhi(v1.y);
            acc[2].x += wb * bflo(v1.z); acc[2].y += wb * bfhi(v1.z);
            acc[3].x += wb * bflo(v1.w); acc[3].y += wb * bfhi(v1.w);
        }
        if (k < deg) {
            int d0 = csr_dst[beg + k];
            float w0 = 0.f;
            if (lane < 8) {
                w0 = edge_w(ssrc + s1d[lane * NN + d0]);
                rsum += w0;
            }
            uint4 v0 = hb[(size_t)d0 * 64 + lane];
            float wa = __shfl(w0, myhead);
            acc[0].x += wa * bflo(v0.x); acc[0].y += wa * bfhi(v0.x);
            acc[1].x += wa * bflo(v0.y); acc[1].y += wa * bfhi(v0.y);
            acc[2].x += wa * bflo(v0.z); acc[2].y += wa * bfhi(v0.z);
            acc[3].x += wa * bflo(v0.w); acc[3].y += wa * bfhi(v0.w);
        }
    }

    float rs = __shfl(rsum, myhead);
    float inv = 1.0f / rs;
    uint4 o;
    o.x = packbf2(elu_f(acc[0].x * inv), elu_f(acc[0].y * inv));
    o.y = packbf2(elu_f(acc[1].x * inv), elu_f(acc[1].y * inv));
    o.z = packbf2(elu_f(acc[2].x * inv), elu_f(acc[2].y * inv));
    o.w = packbf2(elu_f(acc[3].x * inv), elu_f(acc[3].y * inv));
    hcat4[(size_t)n * 64 + lane] = o;
}

// ---------------- GEMM2 (bf16 in) + scores ----------------
__global__ __launch_bounds__(256) void gemm2_k(const uint* __restrict__ hcat2,
                                               const float* __restrict__ W2,
                                               const float* __restrict__ a2,
                                               float* __restrict__ h2,
                                               float* __restrict__ s2s,
                                               float* __restrict__ s2d) {
    __shared__ float Ws[512 * 16];
    for (int i = threadIdx.x; i < 512 * 16; i += 256) Ws[i] = W2[i];
    __syncthreads();
    const int wid = threadIdx.x >> 6;
    const int lane = threadIdx.x & 63;
    const int col = lane & 15;
    const int chunk = lane >> 4;
    for (int n = blockIdx.x * 4 + wid; n < NN; n += gridDim.x * 4) {
        const uint* hr = hcat2 + (size_t)n * 256 + chunk * 64;
        float acc = 0.0f;
#pragma unroll 4
        for (int i = 0; i < 16; i++) {
            uint4 v = *(const uint4*)(hr + i * 4);
            int k = chunk * 128 + i * 8;
            acc += bflo(v.x) * Ws[(k + 0) * 16 + col] + bfhi(v.x) * Ws[(k + 1) * 16 + col] +
                   bflo(v.y) * Ws[(k + 2) * 16 + col] + bfhi(v.y) * Ws[(k + 3) * 16 + col] +
                   bflo(v.z) * Ws[(k + 4) * 16 + col] + bfhi(v.z) * Ws[(k + 5) * 16 + col] +
                   bflo(v.w) * Ws[(k + 6) * 16 + col] + bfhi(v.w) * Ws[(k + 7) * 16 + col];
        }
        acc += __shfl_down(acc, 32);
        acc += __shfl_down(acc, 16);
        if (lane < 16) {
            h2[(size_t)n * 16 + col] = acc;
            float ss = acc * a2[col];
            float sd = acc * a2[16 + col];
#pragma unroll
            for (int o = 8; o > 0; o >>= 1) {
                ss += __shfl_down(ss, o);
                sd += __shfl_down(sd, o);
            }
            if (lane == 0) { s2s[n] = ss; s2d[n] = sd; }
        }
    }
}

// ---------------- layer-2 aggregation + fused log_softmax ----------------
__global__ __launch_bounds__(256) void agg2_k(const int* __restrict__ rowptr,
                                              const int* __restrict__ csr_dst,
                                              const float* __restrict__ s2s,
                                              const float* __restrict__ s2d,
                                              const float* __restrict__ h2,
                                              float* __restrict__ out) {
    const int n = (blockIdx.x * 256 + threadIdx.x) >> 6;
    const int lane = threadIdx.x & 63;
    if (n >= NN) return;
    const int beg = rowptr[n], end = rowptr[n + 1];
    const float sn = s2s[n];
    const int sub = lane >> 4, f = lane & 15;
    float acc = 0.f, rsum = 0.f;
    for (int e = beg + sub; e < end; e += 4) {
        int dst = csr_dst[e];
        float wv = edge_w(sn + s2d[dst]);
        acc += wv * h2[(size_t)dst * 16 + f];
        rsum += wv;
    }
    acc += __shfl_down(acc, 32);
    acc += __shfl_down(acc, 16);
    rsum += __shfl_down(rsum, 32);
    rsum += __shfl_down(rsum, 16);
    if (lane < 16) {
        float v = elu_f(acc / rsum);
        float m = v;
#pragma unroll
        for (int o = 8; o > 0; o >>= 1) m = fmaxf(m, __shfl_xor(m, o));
        float ex = expf(v - m), s = ex;
#pragma unroll
        for (int o = 8; o > 0; o >>= 1) s += __shfl_xor(s, o);
        out[(size_t)n * 16 + f] = v - (logf(s) + m);
    }
}

extern "C" void kernel_launch(void* const* d_in, const int* in_sizes, int n_in,
                              void* d_out, int out_size, void* d_ws, size_t ws_size,
                              hipStream_t stream) {
    const float* x  = (const float*)d_in[0];
    const int*   ei = (const int*)d_in[1];
    const float* W1 = (const float*)d_in[2];
    const float* a1 = (const float*)d_in[3];
    const float* W2 = (const float*)d_in[4];
    const float* a2 = (const float*)d_in[5];
    float* out = (float*)d_out;

    ushort* xb    = (ushort*)d_ws;                 // 25.6M ushort
    ushort* h1b   = xb + (size_t)NN * 512;         // 25.6M
    ushort* hcatb = h1b + (size_t)NN * 512;        // 25.6M
    ushort* Wt    = hcatb + (size_t)NN * 512;      // 262144
    float* s1s    = (float*)(Wt + 512 * 512);      // 400K floats
    float* s1d    = s1s + (size_t)NN * H1;         // 400K
    int* deg      = (int*)(s1d + (size_t)NN * H1); // 50000
    int* cursor   = deg + NN;                      // 50000
    int* rowptr   = cursor + NN;                   // 50001
    int* csr_dst  = rowptr + NN + 1;               // 1.6M
    float* h2     = (float*)(csr_dst + NE);        // 800K
    float* s2s    = h2 + (size_t)NN * 16;          // 50000
    float* s2d    = s2s + NN;                      // 50000

    hipMemsetAsync(deg, 0, 2 * NN * sizeof(int), stream);  // deg + cursor

    cast_x<<<12500, 256, 0, stream>>>((const float4*)x, (uint4*)xb);
    pack_w<<<1024, 256, 0, stream>>>(W1, Wt);
    deg_k<<<(NE + 255) / 256, 256, 0, stream>>>(ei, deg);
    scan_k<<<1, 1024, 0, stream>>>(deg, rowptr);
    scatter_k<<<(NE + 255) / 256, 256, 0, stream>>>(ei, rowptr, cursor, csr_dst);
    gemm1_k<<<dim3(4, 391), 256, 0, stream>>>(xb, Wt, a1, h1b, s1s, s1d);
    agg1_k<<<(NN + 3) / 4, 256, 0, stream>>>(rowptr, csr_dst, s1s, s1d,
                                             (const uint4*)h1b, (uint4*)hcatb);
    gemm2_k<<<2048, 256, 0, stream>>>((const uint*)hcatb, W2, a2, h2, s2s, s2d);
    agg2_k<<<(NN + 3) / 4, 256, 0, stream>>>(rowptr, csr_dst, s2s, s2d, h2, out);
}

// Round 5
// 731.881 us; speedup vs baseline: 5.3955x; 1.0579x over previous
//
#include <hip/hip_runtime.h>

#define NN 50000
#define NE 1600000
#define NFEAT 512
#define NHID 64
#define H1 8
#define NCLASS 16
#define ALPHA 0.2f

typedef __attribute__((ext_vector_type(8))) short short8;
typedef __attribute__((ext_vector_type(4))) float floatx4;

__device__ __forceinline__ float elu_f(float x) { return x > 0.0f ? x : expf(x) - 1.0f; }
__device__ __forceinline__ float edge_w(float logit) {
    return expf(-fmaxf(logit, ALPHA * logit));   // exp(-leaky_relu)
}
__device__ __forceinline__ ushort f2bf(float f) {
    uint u = __float_as_uint(f);
    return (ushort)((u + 0x7FFFu + ((u >> 16) & 1)) >> 16);   // RNE
}
__device__ __forceinline__ uint packbf2(float lo, float hi) {
    return (uint)f2bf(lo) | ((uint)f2bf(hi) << 16);
}
__device__ __forceinline__ float bflo(uint v) { return __uint_as_float(v << 16); }
__device__ __forceinline__ float bfhi(uint v) { return __uint_as_float(v & 0xFFFF0000u); }

// ---------------- phase 0 merged: cast x->bf16 | pack W1 | degree histogram ----------------
#define CAST_BLKS 12500
#define PACK_BLKS 1024
#define DEG_BLKS  6250
__global__ __launch_bounds__(256) void prep_k(const float4* __restrict__ x,
                                              uint4* __restrict__ xb,
                                              const float* __restrict__ W1,
                                              ushort* __restrict__ Wt,
                                              const int* __restrict__ ei,
                                              int* __restrict__ deg) {
    int b = blockIdx.x;
    if (b < CAST_BLKS) {
        size_t i = (size_t)b * 256 + threadIdx.x;
        float4 a = x[2 * i], c = x[2 * i + 1];
        uint4 o;
        o.x = packbf2(a.x, a.y);
        o.y = packbf2(a.z, a.w);
        o.z = packbf2(c.x, c.y);
        o.w = packbf2(c.z, c.w);
        xb[i] = o;
    } else if (b < CAST_BLKS + PACK_BLKS) {
        int i = (b - CAST_BLKS) * 256 + threadIdx.x;
        int c = i >> 9, k = i & 511;
        int head = c >> 6, hid = c & 63;
        Wt[i] = f2bf(W1[(head * 512 + k) * 64 + hid]);
    } else {
        int e = (b - CAST_BLKS - PACK_BLKS) * 256 + threadIdx.x;
        if (e < NE) atomicAdd(&deg[ei[e]], 1);
    }
}

// ---------------- parallel exclusive scan of deg -> rowptr (3 phases) ----------------
#define SCAN_BLKS 196
__global__ __launch_bounds__(256) void scanA_k(const int* __restrict__ deg,
                                               int* __restrict__ rowptr,
                                               int* __restrict__ bsum) {
    __shared__ int wsum[4];
    const int t = threadIdx.x, lane = t & 63, wv = t >> 6;
    int i = blockIdx.x * 256 + t;
    int v = (i < NN) ? deg[i] : 0;
    int s = v;
#pragma unroll
    for (int o = 1; o < 64; o <<= 1) {
        int u = __shfl_up(s, o);
        if (lane >= o) s += u;
    }
    if (lane == 63) wsum[wv] = s;
    __syncthreads();
    if (t == 0) { wsum[1] += wsum[0]; wsum[2] += wsum[1]; wsum[3] += wsum[2]; }
    __syncthreads();
    int excl = s - v + (wv > 0 ? wsum[wv - 1] : 0);
    if (i < NN) rowptr[i] = excl;
    if (t == 255) bsum[blockIdx.x] = wsum[3];
}

__global__ __launch_bounds__(256) void scanB_k(int* __restrict__ bsum) {
    __shared__ int wsum[4];
    const int t = threadIdx.x, lane = t & 63, wv = t >> 6;
    int v = (t < SCAN_BLKS) ? bsum[t] : 0;
    int s = v;
#pragma unroll
    for (int o = 1; o < 64; o <<= 1) {
        int u = __shfl_up(s, o);
        if (lane >= o) s += u;
    }
    if (lane == 63) wsum[wv] = s;
    __syncthreads();
    if (t == 0) { wsum[1] += wsum[0]; wsum[2] += wsum[1]; wsum[3] += wsum[2]; }
    __syncthreads();
    if (t < SCAN_BLKS) bsum[t] = s - v + (wv > 0 ? wsum[wv - 1] : 0);
}

__global__ __launch_bounds__(256) void scanC_k(int* __restrict__ rowptr,
                                               const int* __restrict__ bsum) {
    int i = blockIdx.x * 256 + threadIdx.x;
    if (i < NN) rowptr[i] += bsum[blockIdx.x];
    if (i == 0) rowptr[NN] = NE;
}

__global__ __launch_bounds__(256) void scatter_k(const int* __restrict__ ei,
                                                 const int* __restrict__ rowptr,
                                                 int* __restrict__ cursor,
                                                 int* __restrict__ csr_dst) {
    int e = blockIdx.x * 256 + threadIdx.x;
    if (e < NE) {
        int src = ei[e];
        int pos = rowptr[src] + atomicAdd(&cursor[src], 1);
        csr_dst[pos] = ei[NE + e];
    }
}

// ---------------- GEMM1 (bf16 MFMA) 128x128 tile (2 heads) + fused scores ----------------
__global__ __launch_bounds__(256) void gemm1_k(const ushort* __restrict__ xb,
                                               const ushort* __restrict__ Wt,
                                               const float* __restrict__ a1,
                                               ushort* __restrict__ h1b,
                                               float* __restrict__ s1s,
                                               float* __restrict__ s1d) {
    __shared__ ushort As[128 * 32];   // [m][k]
    __shared__ ushort Bs[128 * 32];   // [c][k]
    const int tid = threadIdx.x;
    const int wv = tid >> 6, lane = tid & 63;
    const int quad = lane >> 4, l16 = lane & 15;
    const int row0 = blockIdx.y * 128;
    const int col0 = blockIdx.x * 128;
    const int sm = tid >> 2, sk = (tid & 3) * 8;
    floatx4 acc[2][8];
#pragma unroll
    for (int rt = 0; rt < 2; rt++)
#pragma unroll
        for (int ct = 0; ct < 8; ct++) acc[rt][ct] = (floatx4){0.f, 0.f, 0.f, 0.f};

    for (int k0 = 0; k0 < 512; k0 += 32) {
#pragma unroll
        for (int p = 0; p < 2; p++) {
            int r = row0 + sm + p * 64;
            uint4 av = make_uint4(0u, 0u, 0u, 0u);
            if (r < NN) av = *(const uint4*)(xb + (size_t)r * 512 + k0 + sk);
            *(uint4*)(As + (sm + p * 64) * 32 + sk) = av;
            int c = col0 + sm + p * 64;
            uint4 bv = *(const uint4*)(Wt + (size_t)c * 512 + k0 + sk);
            *(uint4*)(Bs + (sm + p * 64) * 32 + sk) = bv;
        }
        __syncthreads();
        short8 a0 = *(const short8*)(As + (wv * 32 + l16) * 32 + quad * 8);
        short8 a1f = *(const short8*)(As + (wv * 32 + 16 + l16) * 32 + quad * 8);
#pragma unroll
        for (int ct = 0; ct < 8; ct++) {
            short8 bf = *(const short8*)(Bs + (ct * 16 + l16) * 32 + quad * 8);
            acc[0][ct] = __builtin_amdgcn_mfma_f32_16x16x32_bf16(a0, bf, acc[0][ct], 0, 0, 0);
            acc[1][ct] = __builtin_amdgcn_mfma_f32_16x16x32_bf16(a1f, bf, acc[1][ct], 0, 0, 0);
        }
        __syncthreads();
    }

#pragma unroll
    for (int rt = 0; rt < 2; rt++) {
        const int rbase = row0 + wv * 32 + rt * 16 + quad * 4;
        float ss[2][4] = {}, sd[2][4] = {};
#pragma unroll
        for (int ct = 0; ct < 8; ct++) {
            int colg = col0 + ct * 16 + l16;
            int head = colg >> 6;
            int hh = ct >> 2;
            float avs = a1[head * 128 + (colg & 63)];
            float avd = a1[head * 128 + 64 + (colg & 63)];
#pragma unroll
            for (int r = 0; r < 4; r++) {
                float v = acc[rt][ct][r];
                ss[hh][r] += v * avs;
                sd[hh][r] += v * avd;
                int row = rbase + r;
                if (row < NN) h1b[(size_t)row * 512 + colg] = f2bf(v);
            }
        }
#pragma unroll
        for (int hh = 0; hh < 2; hh++)
#pragma unroll
            for (int r = 0; r < 4; r++) {
                float a_ = ss[hh][r], b_ = sd[hh][r];
#pragma unroll
                for (int o = 1; o < 16; o <<= 1) {
                    a_ += __shfl_xor(a_, o);
                    b_ += __shfl_xor(b_, o);
                }
                int row = rbase + r;
                if (l16 == 0 && row < NN) {
                    int head = (col0 >> 6) + hh;
                    s1s[head * NN + row] = a_;
                    s1d[head * NN + row] = b_;
                }
            }
    }
}

// ---------------- layer-1 aggregation: one wave per node, 8-edge batched ----------------
// lane l covers bf16 feats [8l..8l+8) => head = l>>3, one dwordx4 gather per edge.
// Weights: lane l computes w for edge (l&7), head (l>>3): one scattered load + one exp
// per 8 edges. Gathers 8-unrolled for MLP.
__global__ __launch_bounds__(256) void agg1_k(const int* __restrict__ rowptr,
                                              const int* __restrict__ csr_dst,
                                              const float* __restrict__ s1s,
                                              const float* __restrict__ s1d,
                                              const uint4* __restrict__ hb,
                                              uint4* __restrict__ hcat4) {
    const int n = (blockIdx.x * 256 + threadIdx.x) >> 6;
    const int lane = threadIdx.x & 63;
    if (n >= NN) return;
    const int beg = rowptr[n], end = rowptr[n + 1];
    const int deg = end - beg;
    const int head8 = lane >> 3;   // this lane's head (weights AND output)
    const int esub = lane & 7;
    const float ssrc = s1s[head8 * NN + n];
    float acc[8] = {};
    float rsum = 0.f;

    const bool sorted = (deg <= 64);
    int d = 0x7fffffff;
    if (sorted) {
        d = (lane < deg) ? csr_dst[beg + lane] : 0x7fffffff;
#pragma unroll
        for (int k = 2; k <= 64; k <<= 1)
            for (int j = k >> 1; j > 0; j >>= 1) {
                int o = __shfl_xor(d, j);
                bool up = (lane & k) == 0;
                bool lower = (lane & j) == 0;
                d = (up == lower) ? min(d, o) : max(d, o);
            }
    }

    for (int k = 0; k < deg; k += 8) {
        int jc = min(k + esub, deg - 1);
        int dwj = sorted ? __shfl(d, jc) : csr_dst[beg + jc];
        float w = edge_w(ssrc + s1d[head8 * NN + dwj]);
        if (k + esub >= deg) w = 0.f;
        rsum += w;
        int rem = deg - k;
        if (rem >= 8) {
            int dj[8];
#pragma unroll
            for (int j = 0; j < 8; j++) dj[j] = __shfl(dwj, j);
            uint4 v[8];
#pragma unroll
            for (int j = 0; j < 8; j++) v[j] = hb[(size_t)dj[j] * 64 + lane];
#pragma unroll
            for (int j = 0; j < 8; j++) {
                float wj = __shfl(w, (head8 << 3) + j);
                acc[0] += wj * bflo(v[j].x); acc[1] += wj * bfhi(v[j].x);
                acc[2] += wj * bflo(v[j].y); acc[3] += wj * bfhi(v[j].y);
                acc[4] += wj * bflo(v[j].z); acc[5] += wj * bfhi(v[j].z);
                acc[6] += wj * bflo(v[j].w); acc[7] += wj * bfhi(v[j].w);
            }
        } else {
            for (int j = 0; j < rem; j++) {
                int djs = __shfl(dwj, j);
                uint4 vv = hb[(size_t)djs * 64 + lane];
                float wj = __shfl(w, (head8 << 3) + j);
                acc[0] += wj * bflo(vv.x); acc[1] += wj * bfhi(vv.x);
                acc[2] += wj * bflo(vv.y); acc[3] += wj * bfhi(vv.y);
                acc[4] += wj * bflo(vv.z); acc[5] += wj * bfhi(vv.z);
                acc[6] += wj * bflo(vv.w); acc[7] += wj * bfhi(vv.w);
            }
        }
    }

    // rowsum for this lane's head = sum over its oct (lanes head*8 .. head*8+7)
    rsum += __shfl_xor(rsum, 1);
    rsum += __shfl_xor(rsum, 2);
    rsum += __shfl_xor(rsum, 4);
    float inv = 1.0f / rsum;
    uint4 o;
    o.x = packbf2(elu_f(acc[0] * inv), elu_f(acc[1] * inv));
    o.y = packbf2(elu_f(acc[2] * inv), elu_f(acc[3] * inv));
    o.z = packbf2(elu_f(acc[4] * inv), elu_f(acc[5] * inv));
    o.w = packbf2(elu_f(acc[6] * inv), elu_f(acc[7] * inv));
    hcat4[(size_t)n * 64 + lane] = o;
}

// ---------------- GEMM2 (bf16 in) + scores ----------------
__global__ __launch_bounds__(256) void gemm2_k(const uint* __restrict__ hcat2,
                                               const float* __restrict__ W2,
                                               const float* __restrict__ a2,
                                               float* __restrict__ h2,
                                               float* __restrict__ s2s,
                                               float* __restrict__ s2d) {
    __shared__ float Ws[512 * 16];
    for (int i = threadIdx.x; i < 512 * 16; i += 256) Ws[i] = W2[i];
    __syncthreads();
    const int wid = threadIdx.x >> 6;
    const int lane = threadIdx.x & 63;
    const int col = lane & 15;
    const int chunk = lane >> 4;
    for (int n = blockIdx.x * 4 + wid; n < NN; n += gridDim.x * 4) {
        const uint* hr = hcat2 + (size_t)n * 256 + chunk * 64;
        float acc = 0.0f;
#pragma unroll 4
        for (int i = 0; i < 16; i++) {
            uint4 v = *(const uint4*)(hr + i * 4);
            int k = chunk * 128 + i * 8;
            acc += bflo(v.x) * Ws[(k + 0) * 16 + col] + bfhi(v.x) * Ws[(k + 1) * 16 + col] +
                   bflo(v.y) * Ws[(k + 2) * 16 + col] + bfhi(v.y) * Ws[(k + 3) * 16 + col] +
                   bflo(v.z) * Ws[(k + 4) * 16 + col] + bfhi(v.z) * Ws[(k + 5) * 16 + col] +
                   bflo(v.w) * Ws[(k + 6) * 16 + col] + bfhi(v.w) * Ws[(k + 7) * 16 + col];
        }
        acc += __shfl_down(acc, 32);
        acc += __shfl_down(acc, 16);
        if (lane < 16) {
            h2[(size_t)n * 16 + col] = acc;
            float ss = acc * a2[col];
            float sd = acc * a2[16 + col];
#pragma unroll
            for (int o = 8; o > 0; o >>= 1) {
                ss += __shfl_down(ss, o);
                sd += __shfl_down(sd, o);
            }
            if (lane == 0) { s2s[n] = ss; s2d[n] = sd; }
        }
    }
}

// ---------------- layer-2 aggregation + fused log_softmax ----------------
__global__ __launch_bounds__(256) void agg2_k(const int* __restrict__ rowptr,
                                              const int* __restrict__ csr_dst,
                                              const float* __restrict__ s2s,
                                              const float* __restrict__ s2d,
                                              const float* __restrict__ h2,
                                              float* __restrict__ out) {
    const int n = (blockIdx.x * 256 + threadIdx.x) >> 6;
    const int lane = threadIdx.x & 63;
    if (n >= NN) return;
    const int beg = rowptr[n], end = rowptr[n + 1];
    const float sn = s2s[n];
    const int sub = lane >> 4, f = lane & 15;
    float acc = 0.f, rsum = 0.f;
    for (int e = beg + sub; e < end; e += 4) {
        int dst = csr_dst[e];
        float wv = edge_w(sn + s2d[dst]);
        acc += wv * h2[(size_t)dst * 16 + f];
        rsum += wv;
    }
    acc += __shfl_down(acc, 32);
    acc += __shfl_down(acc, 16);
    rsum += __shfl_down(rsum, 32);
    rsum += __shfl_down(rsum, 16);
    if (lane < 16) {
        float v = elu_f(acc / rsum);
        float m = v;
#pragma unroll
        for (int o = 8; o > 0; o >>= 1) m = fmaxf(m, __shfl_xor(m, o));
        float ex = expf(v - m), s = ex;
#pragma unroll
        for (int o = 8; o > 0; o >>= 1) s += __shfl_xor(s, o);
        out[(size_t)n * 16 + f] = v - (logf(s) + m);
    }
}

extern "C" void kernel_launch(void* const* d_in, const int* in_sizes, int n_in,
                              void* d_out, int out_size, void* d_ws, size_t ws_size,
                              hipStream_t stream) {
    const float* x  = (const float*)d_in[0];
    const int*   ei = (const int*)d_in[1];
    const float* W1 = (const float*)d_in[2];
    const float* a1 = (const float*)d_in[3];
    const float* W2 = (const float*)d_in[4];
    const float* a2 = (const float*)d_in[5];
    float* out = (float*)d_out;

    ushort* xb    = (ushort*)d_ws;                 // 25.6M ushort
    ushort* h1b   = xb + (size_t)NN * 512;         // 25.6M
    ushort* hcatb = h1b + (size_t)NN * 512;        // 25.6M
    ushort* Wt    = hcatb + (size_t)NN * 512;      // 262144
    float* s1s    = (float*)(Wt + 512 * 512);      // 400K floats
    float* s1d    = s1s + (size_t)NN * H1;         // 400K
    int* deg      = (int*)(s1d + (size_t)NN * H1); // 50000
    int* cursor   = deg + NN;                      // 50000
    int* rowptr   = cursor + NN;                   // 50001
    int* csr_dst  = rowptr + NN + 1;               // 1.6M
    int* bsum     = csr_dst + NE;                  // 196
    float* h2     = (float*)(bsum + 256);          // 800K
    float* s2s    = h2 + (size_t)NN * 16;          // 50000
    float* s2d    = s2s + NN;                      // 50000

    hipMemsetAsync(deg, 0, 2 * NN * sizeof(int), stream);  // deg + cursor

    prep_k<<<CAST_BLKS + PACK_BLKS + DEG_BLKS, 256, 0, stream>>>(
        (const float4*)x, (uint4*)xb, W1, Wt, ei, deg);
    scanA_k<<<SCAN_BLKS, 256, 0, stream>>>(deg, rowptr, bsum);
    scanB_k<<<1, 256, 0, stream>>>(bsum);
    scanC_k<<<SCAN_BLKS, 256, 0, stream>>>(rowptr, bsum);
    scatter_k<<<(NE + 255) / 256, 256, 0, stream>>>(ei, rowptr, cursor, csr_dst);
    gemm1_k<<<dim3(4, 391), 256, 0, stream>>>(xb, Wt, a1, h1b, s1s, s1d);
    agg1_k<<<(NN + 3) / 4, 256, 0, stream>>>(rowptr, csr_dst, s1s, s1d,
                                             (const uint4*)h1b, (uint4*)hcatb);
    gemm2_k<<<2048, 256, 0, stream>>>((const uint*)hcatb, W2, a2, h2, s2s, s2d);
    agg2_k<<<(NN + 3) / 4, 256, 0, stream>>>(rowptr, csr_dst, s2s, s2d, h2, out);
}

// Round 6
// 707.397 us; speedup vs baseline: 5.5823x; 1.0346x over previous
//
#include <hip/hip_runtime.h>

#define NN 50000
#define NE 1600000
#define NFEAT 512
#define NHID 64
#define H1 8
#define NCLASS 16
#define ALPHA 0.2f

typedef __attribute__((ext_vector_type(8))) short short8;
typedef __attribute__((ext_vector_type(4))) float floatx4;

__device__ __forceinline__ float elu_f(float x) { return x > 0.0f ? x : expf(x) - 1.0f; }
__device__ __forceinline__ float edge_w(float logit) {
    return expf(-fmaxf(logit, ALPHA * logit));   // exp(-leaky_relu)
}
__device__ __forceinline__ ushort f2bf(float f) {
    uint u = __float_as_uint(f);
    return (ushort)((u + 0x7FFFu + ((u >> 16) & 1)) >> 16);   // RNE
}
__device__ __forceinline__ uint packbf2(float lo, float hi) {
    return (uint)f2bf(lo) | ((uint)f2bf(hi) << 16);
}
__device__ __forceinline__ float bflo(uint v) { return __uint_as_float(v << 16); }
__device__ __forceinline__ float bfhi(uint v) { return __uint_as_float(v & 0xFFFF0000u); }

// ---------------- phase 0 merged: cast x->bf16 | pack W1 | pack W2^T | degree hist ----------------
#define CAST_BLKS 12500
#define PACK_BLKS 1024
#define PACK2_BLKS 32
#define DEG_BLKS  6250
__global__ __launch_bounds__(256) void prep_k(const float4* __restrict__ x,
                                              uint4* __restrict__ xb,
                                              const float* __restrict__ W1,
                                              ushort* __restrict__ Wt,
                                              const float* __restrict__ W2,
                                              ushort* __restrict__ W2tb,
                                              const int* __restrict__ ei,
                                              int* __restrict__ deg) {
    int b = blockIdx.x;
    if (b < CAST_BLKS) {
        size_t i = (size_t)b * 256 + threadIdx.x;
        float4 a = x[2 * i], c = x[2 * i + 1];
        uint4 o;
        o.x = packbf2(a.x, a.y);
        o.y = packbf2(a.z, a.w);
        o.z = packbf2(c.x, c.y);
        o.w = packbf2(c.z, c.w);
        xb[i] = o;
    } else if (b < CAST_BLKS + PACK_BLKS) {
        int i = (b - CAST_BLKS) * 256 + threadIdx.x;
        int c = i >> 9, k = i & 511;
        int head = c >> 6, hid = c & 63;
        Wt[i] = f2bf(W1[(head * 512 + k) * 64 + hid]);
    } else if (b < CAST_BLKS + PACK_BLKS + PACK2_BLKS) {
        int i = (b - CAST_BLKS - PACK_BLKS) * 256 + threadIdx.x;   // i = c*512 + f
        int c = i >> 9, f = i & 511;
        W2tb[i] = f2bf(W2[f * 16 + c]);
    } else {
        int e = (b - CAST_BLKS - PACK_BLKS - PACK2_BLKS) * 256 + threadIdx.x;
        if (e < NE) atomicAdd(&deg[ei[e]], 1);
    }
}

// ---------------- parallel exclusive scan of deg -> rowptr (3 phases) ----------------
#define SCAN_BLKS 196
__global__ __launch_bounds__(256) void scanA_k(const int* __restrict__ deg,
                                               int* __restrict__ rowptr,
                                               int* __restrict__ bsum) {
    __shared__ int wsum[4];
    const int t = threadIdx.x, lane = t & 63, wv = t >> 6;
    int i = blockIdx.x * 256 + t;
    int v = (i < NN) ? deg[i] : 0;
    int s = v;
#pragma unroll
    for (int o = 1; o < 64; o <<= 1) {
        int u = __shfl_up(s, o);
        if (lane >= o) s += u;
    }
    if (lane == 63) wsum[wv] = s;
    __syncthreads();
    if (t == 0) { wsum[1] += wsum[0]; wsum[2] += wsum[1]; wsum[3] += wsum[2]; }
    __syncthreads();
    int excl = s - v + (wv > 0 ? wsum[wv - 1] : 0);
    if (i < NN) rowptr[i] = excl;
    if (t == 255) bsum[blockIdx.x] = wsum[3];
}

__global__ __launch_bounds__(256) void scanB_k(int* __restrict__ bsum) {
    __shared__ int wsum[4];
    const int t = threadIdx.x, lane = t & 63, wv = t >> 6;
    int v = (t < SCAN_BLKS) ? bsum[t] : 0;
    int s = v;
#pragma unroll
    for (int o = 1; o < 64; o <<= 1) {
        int u = __shfl_up(s, o);
        if (lane >= o) s += u;
    }
    if (lane == 63) wsum[wv] = s;
    __syncthreads();
    if (t == 0) { wsum[1] += wsum[0]; wsum[2] += wsum[1]; wsum[3] += wsum[2]; }
    __syncthreads();
    if (t < SCAN_BLKS) bsum[t] = s - v + (wv > 0 ? wsum[wv - 1] : 0);
}

__global__ __launch_bounds__(256) void scanC_k(int* __restrict__ rowptr,
                                               const int* __restrict__ bsum) {
    int i = blockIdx.x * 256 + threadIdx.x;
    if (i < NN) rowptr[i] += bsum[blockIdx.x];
    if (i == 0) rowptr[NN] = NE;
}

__global__ __launch_bounds__(256) void scatter_k(const int* __restrict__ ei,
                                                 const int* __restrict__ rowptr,
                                                 int* __restrict__ cursor,
                                                 int* __restrict__ csr_dst) {
    int e = blockIdx.x * 256 + threadIdx.x;
    if (e < NE) {
        int src = ei[e];
        int pos = rowptr[src] + atomicAdd(&cursor[src], 1);
        csr_dst[pos] = ei[NE + e];
    }
}

// ---------------- GEMM1 (bf16 MFMA) 128x128 tile (2 heads) + fused scores ----------------
__global__ __launch_bounds__(256) void gemm1_k(const ushort* __restrict__ xb,
                                               const ushort* __restrict__ Wt,
                                               const float* __restrict__ a1,
                                               ushort* __restrict__ h1b,
                                               float* __restrict__ s1s,
                                               float* __restrict__ s1d) {
    __shared__ ushort As[128 * 32];   // [m][k]
    __shared__ ushort Bs[128 * 32];   // [c][k]
    const int tid = threadIdx.x;
    const int wv = tid >> 6, lane = tid & 63;
    const int quad = lane >> 4, l16 = lane & 15;
    const int row0 = blockIdx.y * 128;
    const int col0 = blockIdx.x * 128;
    const int sm = tid >> 2, sk = (tid & 3) * 8;
    floatx4 acc[2][8];
#pragma unroll
    for (int rt = 0; rt < 2; rt++)
#pragma unroll
        for (int ct = 0; ct < 8; ct++) acc[rt][ct] = (floatx4){0.f, 0.f, 0.f, 0.f};

    for (int k0 = 0; k0 < 512; k0 += 32) {
#pragma unroll
        for (int p = 0; p < 2; p++) {
            int r = row0 + sm + p * 64;
            uint4 av = make_uint4(0u, 0u, 0u, 0u);
            if (r < NN) av = *(const uint4*)(xb + (size_t)r * 512 + k0 + sk);
            *(uint4*)(As + (sm + p * 64) * 32 + sk) = av;
            int c = col0 + sm + p * 64;
            uint4 bv = *(const uint4*)(Wt + (size_t)c * 512 + k0 + sk);
            *(uint4*)(Bs + (sm + p * 64) * 32 + sk) = bv;
        }
        __syncthreads();
        short8 a0 = *(const short8*)(As + (wv * 32 + l16) * 32 + quad * 8);
        short8 a1f = *(const short8*)(As + (wv * 32 + 16 + l16) * 32 + quad * 8);
#pragma unroll
        for (int ct = 0; ct < 8; ct++) {
            short8 bf = *(const short8*)(Bs + (ct * 16 + l16) * 32 + quad * 8);
            acc[0][ct] = __builtin_amdgcn_mfma_f32_16x16x32_bf16(a0, bf, acc[0][ct], 0, 0, 0);
            acc[1][ct] = __builtin_amdgcn_mfma_f32_16x16x32_bf16(a1f, bf, acc[1][ct], 0, 0, 0);
        }
        __syncthreads();
    }

#pragma unroll
    for (int rt = 0; rt < 2; rt++) {
        const int rbase = row0 + wv * 32 + rt * 16 + quad * 4;
        float ss[2][4] = {}, sd[2][4] = {};
#pragma unroll
        for (int ct = 0; ct < 8; ct++) {
            int colg = col0 + ct * 16 + l16;
            int head = colg >> 6;
            int hh = ct >> 2;
            float avs = a1[head * 128 + (colg & 63)];
            float avd = a1[head * 128 + 64 + (colg & 63)];
#pragma unroll
            for (int r = 0; r < 4; r++) {
                float v = acc[rt][ct][r];
                ss[hh][r] += v * avs;
                sd[hh][r] += v * avd;
                int row = rbase + r;
                if (row < NN) h1b[(size_t)row * 512 + colg] = f2bf(v);
            }
        }
#pragma unroll
        for (int hh = 0; hh < 2; hh++)
#pragma unroll
            for (int r = 0; r < 4; r++) {
                float a_ = ss[hh][r], b_ = sd[hh][r];
#pragma unroll
                for (int o = 1; o < 16; o <<= 1) {
                    a_ += __shfl_xor(a_, o);
                    b_ += __shfl_xor(b_, o);
                }
                int row = rbase + r;
                if (l16 == 0 && row < NN) {
                    int head = (col0 >> 6) + hh;
                    s1s[head * NN + row] = a_;
                    s1d[head * NN + row] = b_;
                }
            }
    }
}

// ---------------- fused layer-1 aggregation + GEMM2 + layer-2 scores ----------------
// One wave per node (4/block). Per-wave: register aggregation over CSR edges
// (lane l covers bf16 feats [8l,8l+8), head = l>>3, one dwordx4 gather/edge;
// batched weights: lane computes edge (l&7) head (l>>3)). Epilogue: stage the
// 4 nodes' hcat rows (bf16) in LDS, wave 0 runs gemm2 as 16 MFMA (M=4-in-16,
// N=16, K=512) and writes h2 + s2s/s2d. hcat never touches HBM.
__global__ __launch_bounds__(256) void agg1f_k(const int* __restrict__ rowptr,
                                               const int* __restrict__ csr_dst,
                                               const float* __restrict__ s1s,
                                               const float* __restrict__ s1d,
                                               const uint4* __restrict__ hb,
                                               const ushort* __restrict__ W2tb,
                                               const float* __restrict__ a2,
                                               float* __restrict__ h2,
                                               float* __restrict__ s2s,
                                               float* __restrict__ s2d) {
    __shared__ ushort Ash[16 * 512];   // rows 0-3: this block's hcat rows (bf16)
    const int tid = threadIdx.x;
    const int wv = tid >> 6, lane = tid & 63;
    const int n0 = blockIdx.x * 4;
    const int n = n0 + wv;              // NN % 4 == 0 -> always valid
    const int head8 = lane >> 3;
    const int esub = lane & 7;
    const int beg = rowptr[n];
    const int deg = rowptr[n + 1] - beg;
    const float ssrc = s1s[head8 * NN + n];
    float acc[8] = {};
    float rsum = 0.f;

    for (int k = 0; k < deg; k += 8) {
        int jc = min(k + esub, deg - 1);
        int dwj = csr_dst[beg + jc];
        float w = edge_w(ssrc + s1d[head8 * NN + dwj]);
        if (k + esub >= deg) w = 0.f;
        rsum += w;
        int rem = deg - k;
        if (rem >= 8) {
            int dj[8];
#pragma unroll
            for (int j = 0; j < 8; j++) dj[j] = __shfl(dwj, j);
            uint4 v[8];
#pragma unroll
            for (int j = 0; j < 8; j++) v[j] = hb[(size_t)dj[j] * 64 + lane];
#pragma unroll
            for (int j = 0; j < 8; j++) {
                float wj = __shfl(w, (head8 << 3) + j);
                acc[0] += wj * bflo(v[j].x); acc[1] += wj * bfhi(v[j].x);
                acc[2] += wj * bflo(v[j].y); acc[3] += wj * bfhi(v[j].y);
                acc[4] += wj * bflo(v[j].z); acc[5] += wj * bfhi(v[j].z);
                acc[6] += wj * bflo(v[j].w); acc[7] += wj * bfhi(v[j].w);
            }
        } else {
            for (int j = 0; j < rem; j++) {
                int djs = __shfl(dwj, j);
                uint4 vv = hb[(size_t)djs * 64 + lane];
                float wj = __shfl(w, (head8 << 3) + j);
                acc[0] += wj * bflo(vv.x); acc[1] += wj * bfhi(vv.x);
                acc[2] += wj * bflo(vv.y); acc[3] += wj * bfhi(vv.y);
                acc[4] += wj * bflo(vv.z); acc[5] += wj * bfhi(vv.z);
                acc[6] += wj * bflo(vv.w); acc[7] += wj * bfhi(vv.w);
            }
        }
    }

    // per-head rowsum: reduce within the oct (lanes head*8 .. head*8+7)
    rsum += __shfl_xor(rsum, 1);
    rsum += __shfl_xor(rsum, 2);
    rsum += __shfl_xor(rsum, 4);
    float inv = 1.0f / rsum;
    uint4 o;
    o.x = packbf2(elu_f(acc[0] * inv), elu_f(acc[1] * inv));
    o.y = packbf2(elu_f(acc[2] * inv), elu_f(acc[3] * inv));
    o.z = packbf2(elu_f(acc[4] * inv), elu_f(acc[5] * inv));
    o.w = packbf2(elu_f(acc[6] * inv), elu_f(acc[7] * inv));
    *(uint4*)(Ash + wv * 512 + lane * 8) = o;   // hcat row wv, feats 8l..8l+7
    __syncthreads();

    if (wv == 0) {
        const int l16 = lane & 15, q = lane >> 4;
        floatx4 c2 = (floatx4){0.f, 0.f, 0.f, 0.f};
#pragma unroll
        for (int s = 0; s < 16; s++) {
            short8 af = *(const short8*)(Ash + l16 * 512 + s * 32 + q * 8);
            short8 bf = *(const short8*)(W2tb + l16 * 512 + s * 32 + q * 8);
            c2 = __builtin_amdgcn_mfma_f32_16x16x32_bf16(af, bf, c2, 0, 0, 0);
        }
        // C[row=q*4+r][col=l16]; rows 0..3 (q==0) are this block's nodes
        if (q == 0) {
#pragma unroll
            for (int r = 0; r < 4; r++) h2[(size_t)(n0 + r) * 16 + l16] = c2[r];
        }
#pragma unroll
        for (int r = 0; r < 4; r++) {
            float ssv = c2[r] * a2[l16];
            float sdv = c2[r] * a2[16 + l16];
#pragma unroll
            for (int oo = 1; oo < 16; oo <<= 1) {
                ssv += __shfl_xor(ssv, oo);
                sdv += __shfl_xor(sdv, oo);
            }
            if (lane == 0) { s2s[n0 + r] = ssv; s2d[n0 + r] = sdv; }
        }
    }
}

// ---------------- layer-2 aggregation + fused log_softmax ----------------
__global__ __launch_bounds__(256) void agg2_k(const int* __restrict__ rowptr,
                                              const int* __restrict__ csr_dst,
                                              const float* __restrict__ s2s,
                                              const float* __restrict__ s2d,
                                              const float* __restrict__ h2,
                                              float* __restrict__ out) {
    const int n = (blockIdx.x * 256 + threadIdx.x) >> 6;
    const int lane = threadIdx.x & 63;
    if (n >= NN) return;
    const int beg = rowptr[n], end = rowptr[n + 1];
    const float sn = s2s[n];
    const int sub = lane >> 4, f = lane & 15;
    float acc = 0.f, rsum = 0.f;
    for (int e = beg + sub; e < end; e += 4) {
        int dst = csr_dst[e];
        float wv = edge_w(sn + s2d[dst]);
        acc += wv * h2[(size_t)dst * 16 + f];
        rsum += wv;
    }
    acc += __shfl_down(acc, 32);
    acc += __shfl_down(acc, 16);
    rsum += __shfl_down(rsum, 32);
    rsum += __shfl_down(rsum, 16);
    if (lane < 16) {
        float v = elu_f(acc / rsum);
        float m = v;
#pragma unroll
        for (int o = 8; o > 0; o >>= 1) m = fmaxf(m, __shfl_xor(m, o));
        float ex = expf(v - m), s = ex;
#pragma unroll
        for (int o = 8; o > 0; o >>= 1) s += __shfl_xor(s, o);
        out[(size_t)n * 16 + f] = v - (logf(s) + m);
    }
}

extern "C" void kernel_launch(void* const* d_in, const int* in_sizes, int n_in,
                              void* d_out, int out_size, void* d_ws, size_t ws_size,
                              hipStream_t stream) {
    const float* x  = (const float*)d_in[0];
    const int*   ei = (const int*)d_in[1];
    const float* W1 = (const float*)d_in[2];
    const float* a1 = (const float*)d_in[3];
    const float* W2 = (const float*)d_in[4];
    const float* a2 = (const float*)d_in[5];
    float* out = (float*)d_out;

    ushort* xb    = (ushort*)d_ws;                 // 25.6M ushort
    ushort* h1b   = xb + (size_t)NN * 512;         // 25.6M
    ushort* Wt    = h1b + (size_t)NN * 512;        // 262144
    ushort* W2tb  = Wt + 512 * 512;                // 8192
    float* s1s    = (float*)(W2tb + 8192);         // 400K floats
    float* s1d    = s1s + (size_t)NN * H1;         // 400K
    int* deg      = (int*)(s1d + (size_t)NN * H1); // 50000
    int* cursor   = deg + NN;                      // 50000
    int* rowptr   = cursor + NN;                   // 50001
    int* csr_dst  = rowptr + NN + 1;               // 1.6M
    int* bsum     = csr_dst + NE;                  // 196
    float* h2     = (float*)(bsum + 256);          // 800K
    float* s2s    = h2 + (size_t)NN * 16;          // 50000
    float* s2d    = s2s + NN;                      // 50000

    hipMemsetAsync(deg, 0, 2 * NN * sizeof(int), stream);  // deg + cursor

    prep_k<<<CAST_BLKS + PACK_BLKS + PACK2_BLKS + DEG_BLKS, 256, 0, stream>>>(
        (const float4*)x, (uint4*)xb, W1, Wt, W2, W2tb, ei, deg);
    scanA_k<<<SCAN_BLKS, 256, 0, stream>>>(deg, rowptr, bsum);
    scanB_k<<<1, 256, 0, stream>>>(bsum);
    scanC_k<<<SCAN_BLKS, 256, 0, stream>>>(rowptr, bsum);
    scatter_k<<<(NE + 255) / 256, 256, 0, stream>>>(ei, rowptr, cursor, csr_dst);
    gemm1_k<<<dim3(4, 391), 256, 0, stream>>>(xb, Wt, a1, h1b, s1s, s1d);
    agg1f_k<<<NN / 4, 256, 0, stream>>>(rowptr, csr_dst, s1s, s1d,
                                        (const uint4*)h1b, W2tb, a2, h2, s2s, s2d);
    agg2_k<<<(NN + 3) / 4, 256, 0, stream>>>(rowptr, csr_dst, s2s, s2d, h2, out);
}